// Round 1
// baseline (76.290 us; speedup 1.0000x reference)
//
#include <hip/hip_runtime.h>

#define BATCH 524288
#define NQ 4
#define TPB 256
#define V 4   // samples per thread

// Single kernel: lanes 0..15 of each block build the weight-only 16x16 unitary U
// into LDS (redundant per block, ~500 cyc), then all 256 threads evaluate V
// samples each: s = kron of per-qubit (cos,sin), amp = U s, probs -> <Z_i>.
__global__ __launch_bounds__(TPB) void qlayer_kernel(const float* __restrict__ x,
                                                     const float* __restrict__ w,
                                                     float* __restrict__ out) {
    __shared__ float Ure[16][16];  // [row j][col k]
    __shared__ float Uim[16][16];

    const int tid = threadIdx.x;

    // ---- Build U columns: thread k evolves basis state e_k through the layers ----
    if (tid < 16) {
        float stx[16], sty[16];
        #pragma unroll
        for (int i = 0; i < 16; i++) { stx[i] = 0.f; sty[i] = 0.f; }
        stx[tid] = 1.f;

        #pragma unroll
        for (int l = 0; l < 2; l++) {
            #pragma unroll
            for (int q = 0; q < 4; q++) {
                float cz, sz, cy, sy;
                __sincosf(0.5f * w[l * 8 + q * 2 + 0], &sz, &cz);
                __sincosf(0.5f * w[l * 8 + q * 2 + 1], &sy, &cy);
                const int mask = 8 >> q;
                // RZ(t) = diag(e^{-it/2}, e^{+it/2})
                #pragma unroll
                for (int i = 0; i < 16; i++) {
                    float ax = stx[i], ay = sty[i];
                    if (i & mask) { stx[i] = ax * cz - ay * sz; sty[i] = ay * cz + ax * sz; }
                    else          { stx[i] = ax * cz + ay * sz; sty[i] = ay * cz - ax * sz; }
                }
                // RY(t) = [[c,-s],[s,c]]
                #pragma unroll
                for (int i = 0; i < 16; i++) {
                    if (!(i & mask)) {
                        float a0x = stx[i], a0y = sty[i];
                        float a1x = stx[i | mask], a1y = sty[i | mask];
                        stx[i]        = cy * a0x - sy * a1x;
                        sty[i]        = cy * a0y - sy * a1y;
                        stx[i | mask] = sy * a0x + cy * a1x;
                        sty[i | mask] = sy * a0y + cy * a1y;
                    }
                }
            }
            // CNOT ring: (0,1),(1,2),(2,3),(3,0); wire 0 is MSB (bit 3 of idx)
            #pragma unroll
            for (int e = 0; e < 4; e++) {
                const int cqs[4] = {0, 1, 2, 3};
                const int tqs[4] = {1, 2, 3, 0};
                const int cm = 8 >> cqs[e];
                const int tm = 8 >> tqs[e];
                #pragma unroll
                for (int i = 0; i < 16; i++) {
                    if ((i & cm) && !(i & tm)) {
                        float t0x = stx[i], t0y = sty[i];
                        stx[i] = stx[i | tm]; sty[i] = sty[i | tm];
                        stx[i | tm] = t0x;    sty[i | tm] = t0y;
                    }
                }
            }
        }
        #pragma unroll
        for (int j = 0; j < 16; j++) { Ure[j][tid] = stx[j]; Uim[j][tid] = sty[j]; }
    }
    __syncthreads();

    // ---- Per-sample evaluation, V samples per thread (stride TPB => coalesced) ----
    const int base = blockIdx.x * (TPB * V) + tid;

    float sv[V][16];
    #pragma unroll
    for (int v = 0; v < V; v++) {
        const int smp = base + v * TPB;
        const float4 xv = reinterpret_cast<const float4*>(x)[smp];
        float c0, s0, c1, s1, c2, s2, c3, s3;
        __sincosf(0.5f * xv.x, &s0, &c0);
        __sincosf(0.5f * xv.y, &s1, &c1);
        __sincosf(0.5f * xv.z, &s2, &c2);
        __sincosf(0.5f * xv.w, &s3, &c3);
        const float p01[4] = {c0 * c1, c0 * s1, s0 * c1, s0 * s1};
        const float p23[4] = {c2 * c3, c2 * s3, s2 * c3, s2 * s3};
        #pragma unroll
        for (int i = 0; i < 16; i++) sv[v][i] = p01[i >> 2] * p23[i & 3];
    }

    float z[V][4];
    #pragma unroll
    for (int v = 0; v < V; v++)
        #pragma unroll
        for (int i = 0; i < 4; i++) z[v][i] = 0.f;

    #pragma unroll
    for (int j = 0; j < 16; j++) {
        // Broadcast-load row j of U (conflict-free: all lanes same address)
        float urow[16], irow[16];
        #pragma unroll
        for (int kk = 0; kk < 4; kk++) {
            const float4 a = reinterpret_cast<const float4*>(&Ure[j][0])[kk];
            const float4 b = reinterpret_cast<const float4*>(&Uim[j][0])[kk];
            urow[4 * kk + 0] = a.x; urow[4 * kk + 1] = a.y;
            urow[4 * kk + 2] = a.z; urow[4 * kk + 3] = a.w;
            irow[4 * kk + 0] = b.x; irow[4 * kk + 1] = b.y;
            irow[4 * kk + 2] = b.z; irow[4 * kk + 3] = b.w;
        }
        #pragma unroll
        for (int v = 0; v < V; v++) {
            float re = 0.f, im = 0.f;
            #pragma unroll
            for (int k = 0; k < 16; k++) {
                re = fmaf(urow[k], sv[v][k], re);
                im = fmaf(irow[k], sv[v][k], im);
            }
            const float p = re * re + im * im;
            z[v][0] += (j & 8) ? -p : p;
            z[v][1] += (j & 4) ? -p : p;
            z[v][2] += (j & 2) ? -p : p;
            z[v][3] += (j & 1) ? -p : p;
        }
    }

    #pragma unroll
    for (int v = 0; v < V; v++) {
        const int smp = base + v * TPB;
        reinterpret_cast<float4*>(out)[smp] = make_float4(z[v][0], z[v][1], z[v][2], z[v][3]);
    }
}

extern "C" void kernel_launch(void* const* d_in, const int* in_sizes, int n_in,
                              void* d_out, int out_size, void* d_ws, size_t ws_size,
                              hipStream_t stream) {
    const float* x = (const float*)d_in[0];
    const float* w = (const float*)d_in[1];
    float* out = (float*)d_out;
    const int grid = BATCH / (TPB * V);  // 512 blocks
    qlayer_kernel<<<grid, TPB, 0, stream>>>(x, w, out);
}

// Round 2
// 72.818 us; speedup vs baseline: 1.0477x; 1.0477x over previous
//
#include <hip/hip_runtime.h>

#define BATCH 524288
#define NQ 4
#define TPB 256
#define V 2   // samples per thread (R2: was 4 — cut register pressure, double TLP)

// Single kernel: lanes 0..15 of each block build the weight-only 16x16 unitary U
// into LDS (redundant per block), then all 256 threads evaluate V samples each:
// s = kron of per-qubit (cos,sin), amp = U s, probs -> <Z_i>.
__global__ __launch_bounds__(TPB, 2) void qlayer_kernel(const float* __restrict__ x,
                                                        const float* __restrict__ w,
                                                        float* __restrict__ out) {
    __shared__ float Ure[16][16];  // [row j][col k]
    __shared__ float Uim[16][16];

    const int tid = threadIdx.x;

    // ---- Build U columns: thread k evolves basis state e_k through the layers ----
    if (tid < 16) {
        float stx[16], sty[16];
        #pragma unroll
        for (int i = 0; i < 16; i++) { stx[i] = 0.f; sty[i] = 0.f; }
        stx[tid] = 1.f;

        #pragma unroll
        for (int l = 0; l < 2; l++) {
            #pragma unroll
            for (int q = 0; q < 4; q++) {
                float cz, sz, cy, sy;
                __sincosf(0.5f * w[l * 8 + q * 2 + 0], &sz, &cz);
                __sincosf(0.5f * w[l * 8 + q * 2 + 1], &sy, &cy);
                const int mask = 8 >> q;
                // RZ(t) = diag(e^{-it/2}, e^{+it/2})
                #pragma unroll
                for (int i = 0; i < 16; i++) {
                    float ax = stx[i], ay = sty[i];
                    if (i & mask) { stx[i] = ax * cz - ay * sz; sty[i] = ay * cz + ax * sz; }
                    else          { stx[i] = ax * cz + ay * sz; sty[i] = ay * cz - ax * sz; }
                }
                // RY(t) = [[c,-s],[s,c]]
                #pragma unroll
                for (int i = 0; i < 16; i++) {
                    if (!(i & mask)) {
                        float a0x = stx[i], a0y = sty[i];
                        float a1x = stx[i | mask], a1y = sty[i | mask];
                        stx[i]        = cy * a0x - sy * a1x;
                        sty[i]        = cy * a0y - sy * a1y;
                        stx[i | mask] = sy * a0x + cy * a1x;
                        sty[i | mask] = sy * a0y + cy * a1y;
                    }
                }
            }
            // CNOT ring: (0,1),(1,2),(2,3),(3,0); wire 0 is MSB (bit 3 of idx)
            #pragma unroll
            for (int e = 0; e < 4; e++) {
                const int cqs[4] = {0, 1, 2, 3};
                const int tqs[4] = {1, 2, 3, 0};
                const int cm = 8 >> cqs[e];
                const int tm = 8 >> tqs[e];
                #pragma unroll
                for (int i = 0; i < 16; i++) {
                    if ((i & cm) && !(i & tm)) {
                        float t0x = stx[i], t0y = sty[i];
                        stx[i] = stx[i | tm]; sty[i] = sty[i | tm];
                        stx[i | tm] = t0x;    sty[i | tm] = t0y;
                    }
                }
            }
        }
        #pragma unroll
        for (int j = 0; j < 16; j++) { Ure[j][tid] = stx[j]; Uim[j][tid] = sty[j]; }
    }
    __syncthreads();

    // ---- Per-sample evaluation, V samples per thread (stride TPB => coalesced) ----
    const int base = blockIdx.x * (TPB * V) + tid;

    float sv[V][16];
    #pragma unroll
    for (int v = 0; v < V; v++) {
        const int smp = base + v * TPB;
        const float4 xv = reinterpret_cast<const float4*>(x)[smp];
        float c0, s0, c1, s1, c2, s2, c3, s3;
        __sincosf(0.5f * xv.x, &s0, &c0);
        __sincosf(0.5f * xv.y, &s1, &c1);
        __sincosf(0.5f * xv.z, &s2, &c2);
        __sincosf(0.5f * xv.w, &s3, &c3);
        const float p01[4] = {c0 * c1, c0 * s1, s0 * c1, s0 * s1};
        const float p23[4] = {c2 * c3, c2 * s3, s2 * c3, s2 * s3};
        #pragma unroll
        for (int i = 0; i < 16; i++) sv[v][i] = p01[i >> 2] * p23[i & 3];
    }

    float z[V][4];
    #pragma unroll
    for (int v = 0; v < V; v++)
        #pragma unroll
        for (int i = 0; i < 4; i++) z[v][i] = 0.f;

    #pragma unroll
    for (int j = 0; j < 16; j++) {
        // Broadcast-load row j of U (conflict-free: all lanes same address)
        float urow[16], irow[16];
        #pragma unroll
        for (int kk = 0; kk < 4; kk++) {
            const float4 a = reinterpret_cast<const float4*>(&Ure[j][0])[kk];
            const float4 b = reinterpret_cast<const float4*>(&Uim[j][0])[kk];
            urow[4 * kk + 0] = a.x; urow[4 * kk + 1] = a.y;
            urow[4 * kk + 2] = a.z; urow[4 * kk + 3] = a.w;
            irow[4 * kk + 0] = b.x; irow[4 * kk + 1] = b.y;
            irow[4 * kk + 2] = b.z; irow[4 * kk + 3] = b.w;
        }
        #pragma unroll
        for (int v = 0; v < V; v++) {
            float re = 0.f, im = 0.f;
            #pragma unroll
            for (int k = 0; k < 16; k++) {
                re = fmaf(urow[k], sv[v][k], re);
                im = fmaf(irow[k], sv[v][k], im);
            }
            const float p = re * re + im * im;
            z[v][0] += (j & 8) ? -p : p;
            z[v][1] += (j & 4) ? -p : p;
            z[v][2] += (j & 2) ? -p : p;
            z[v][3] += (j & 1) ? -p : p;
        }
    }

    #pragma unroll
    for (int v = 0; v < V; v++) {
        const int smp = base + v * TPB;
        reinterpret_cast<float4*>(out)[smp] = make_float4(z[v][0], z[v][1], z[v][2], z[v][3]);
    }
}

extern "C" void kernel_launch(void* const* d_in, const int* in_sizes, int n_in,
                              void* d_out, int out_size, void* d_ws, size_t ws_size,
                              hipStream_t stream) {
    const float* x = (const float*)d_in[0];
    const float* w = (const float*)d_in[1];
    float* out = (float*)d_out;
    const int grid = BATCH / (TPB * V);  // 1024 blocks -> 4 blocks/CU, 16 waves/CU
    qlayer_kernel<<<grid, TPB, 0, stream>>>(x, w, out);
}

// Round 3
// 69.242 us; speedup vs baseline: 1.1018x; 1.0516x over previous
//
#include <hip/hip_runtime.h>

#define BATCH 524288
#define TPB 256
#define V 2   // samples per thread

// ---------------------------------------------------------------------------
// Kernel 1 (tiny): build the weight-only 16x16 unitary U and write it to d_ws
// row-major: ws[j*32 + k] = Re U[j][k], ws[j*32 + 16 + k] = Im U[j][k].
// Thread k evolves basis state e_k (column k); writes transposed -> rows.
// ---------------------------------------------------------------------------
__global__ void qprep_kernel(const float* __restrict__ w, float* __restrict__ ws) {
    const int tid = threadIdx.x;
    if (tid >= 16) return;

    float stx[16], sty[16];
    #pragma unroll
    for (int i = 0; i < 16; i++) { stx[i] = 0.f; sty[i] = 0.f; }
    stx[tid] = 1.f;

    #pragma unroll
    for (int l = 0; l < 2; l++) {
        #pragma unroll
        for (int q = 0; q < 4; q++) {
            float cz, sz, cy, sy;
            __sincosf(0.5f * w[l * 8 + q * 2 + 0], &sz, &cz);
            __sincosf(0.5f * w[l * 8 + q * 2 + 1], &sy, &cy);
            const int mask = 8 >> q;
            // RZ(t) = diag(e^{-it/2}, e^{+it/2})
            #pragma unroll
            for (int i = 0; i < 16; i++) {
                float ax = stx[i], ay = sty[i];
                if (i & mask) { stx[i] = ax * cz - ay * sz; sty[i] = ay * cz + ax * sz; }
                else          { stx[i] = ax * cz + ay * sz; sty[i] = ay * cz - ax * sz; }
            }
            // RY(t) = [[c,-s],[s,c]]
            #pragma unroll
            for (int i = 0; i < 16; i++) {
                if (!(i & mask)) {
                    float a0x = stx[i], a0y = sty[i];
                    float a1x = stx[i | mask], a1y = sty[i | mask];
                    stx[i]        = cy * a0x - sy * a1x;
                    sty[i]        = cy * a0y - sy * a1y;
                    stx[i | mask] = sy * a0x + cy * a1x;
                    sty[i | mask] = sy * a0y + cy * a1y;
                }
            }
        }
        // CNOT ring (0,1),(1,2),(2,3),(3,0); wire 0 is MSB (bit 3)
        #pragma unroll
        for (int e = 0; e < 4; e++) {
            const int cqs[4] = {0, 1, 2, 3};
            const int tqs[4] = {1, 2, 3, 0};
            const int cm = 8 >> cqs[e];
            const int tm = 8 >> tqs[e];
            #pragma unroll
            for (int i = 0; i < 16; i++) {
                if ((i & cm) && !(i & tm)) {
                    float t0x = stx[i], t0y = sty[i];
                    stx[i] = stx[i | tm]; sty[i] = sty[i | tm];
                    stx[i | tm] = t0x;    sty[i | tm] = t0y;
                }
            }
        }
    }
    #pragma unroll
    for (int j = 0; j < 16; j++) {
        ws[j * 32 + tid]      = stx[j];   // Re U[j][tid]
        ws[j * 32 + 16 + tid] = sty[j];   // Im U[j][tid]
    }
}

// ---------------------------------------------------------------------------
// Kernel 2 (hot): per-sample evaluation. U accessed with wave-uniform indices
// from a read-only __restrict__ pointer -> compiler scalarizes to s_load,
// U rows live in SGPRs, v_fma uses the SGPR operand. No LDS, no barriers.
// ---------------------------------------------------------------------------
__global__ __launch_bounds__(TPB, 4) void qmain_kernel(const float* __restrict__ x,
                                                       const float* __restrict__ U,
                                                       float* __restrict__ out) {
    const int base = blockIdx.x * (TPB * V) + threadIdx.x;

    float sv[V][16];
    #pragma unroll
    for (int v = 0; v < V; v++) {
        const int smp = base + v * TPB;
        const float4 xv = reinterpret_cast<const float4*>(x)[smp];
        float c0, s0, c1, s1, c2, s2, c3, s3;
        __sincosf(0.5f * xv.x, &s0, &c0);
        __sincosf(0.5f * xv.y, &s1, &c1);
        __sincosf(0.5f * xv.z, &s2, &c2);
        __sincosf(0.5f * xv.w, &s3, &c3);
        const float p01[4] = {c0 * c1, c0 * s1, s0 * c1, s0 * s1};
        const float p23[4] = {c2 * c3, c2 * s3, s2 * c3, s2 * s3};
        #pragma unroll
        for (int i = 0; i < 16; i++) sv[v][i] = p01[i >> 2] * p23[i & 3];
    }

    float z[V][4];
    #pragma unroll
    for (int v = 0; v < V; v++)
        #pragma unroll
        for (int i = 0; i < 4; i++) z[v][i] = 0.f;

    #pragma unroll
    for (int j = 0; j < 16; j++) {
        float re[V], im[V];
        #pragma unroll
        for (int v = 0; v < V; v++) { re[v] = 0.f; im[v] = 0.f; }
        #pragma unroll
        for (int k = 0; k < 16; k++) {
            const float ur = U[j * 32 + k];        // uniform -> SGPR
            const float ui = U[j * 32 + 16 + k];   // uniform -> SGPR
            #pragma unroll
            for (int v = 0; v < V; v++) {
                re[v] = fmaf(ur, sv[v][k], re[v]);
                im[v] = fmaf(ui, sv[v][k], im[v]);
            }
        }
        #pragma unroll
        for (int v = 0; v < V; v++) {
            const float p = re[v] * re[v] + im[v] * im[v];
            z[v][0] += (j & 8) ? -p : p;
            z[v][1] += (j & 4) ? -p : p;
            z[v][2] += (j & 2) ? -p : p;
            z[v][3] += (j & 1) ? -p : p;
        }
    }

    #pragma unroll
    for (int v = 0; v < V; v++) {
        const int smp = base + v * TPB;
        reinterpret_cast<float4*>(out)[smp] = make_float4(z[v][0], z[v][1], z[v][2], z[v][3]);
    }
}

extern "C" void kernel_launch(void* const* d_in, const int* in_sizes, int n_in,
                              void* d_out, int out_size, void* d_ws, size_t ws_size,
                              hipStream_t stream) {
    const float* x = (const float*)d_in[0];
    const float* w = (const float*)d_in[1];
    float* out = (float*)d_out;
    float* U = (float*)d_ws;  // 512 floats

    qprep_kernel<<<1, 64, 0, stream>>>(w, U);
    const int grid = BATCH / (TPB * V);  // 1024 blocks
    qmain_kernel<<<grid, TPB, 0, stream>>>(x, U, out);
}